// Round 1
// 236.053 us; speedup vs baseline: 1.0336x; 1.0336x over previous
//
#include <hip/hip_runtime.h>
#include <hip/hip_bf16.h>
#include <hip/hip_fp16.h>

#define N_NODES 50000
#define N_EDGES 800000
#define DIM 128

#define NBUCK 391      // ceil(N/128) buckets of 128 consecutive dst nodes
#define BCAP  2816     // per-bucket staging capacity (mean 2046, sigma 45 -> +17 sigma)
#define CHUNK 2048     // edges per partition block (391 blocks)

#define CVT_BLOCKS 25000   // 25000*256 == N_NODES*DIM exactly

#define LDSROW 136     // Gs row stride in shorts (272 B: 2-way bank alias = free)

typedef float floatx4 __attribute__((ext_vector_type(4)));
typedef float floatx2 __attribute__((ext_vector_type(2)));
typedef short shortx8 __attribute__((ext_vector_type(8)));

__device__ __forceinline__ unsigned short f2bf(float f) {
    union { float f; unsigned int u; } c; c.f = f;
    unsigned int u = c.u;
    unsigned int r = (u + 0x7FFFu + ((u >> 16) & 1u)) >> 16;
    return (unsigned short)r;
}
// unpack u32 (2 bf16) -> packed float2 (feeds v_pk_fma_f32)
__device__ __forceinline__ floatx2 bf2x2(unsigned int p) {
    union { unsigned int u; float f; } lo, hi;
    lo.u = p << 16; hi.u = p & 0xFFFF0000u;
    return (floatx2){lo.f, hi.f};
}

// ---------------------------------------------------------------------------
// prep: fused  x->bf16 convert | zero bcursor | weight pack
__global__ __launch_bounds__(256)
void prep_kernel(const float* __restrict__ x, unsigned short* __restrict__ X,
                 const float* __restrict__ wr0, const float* __restrict__ wt0,
                 const float* __restrict__ wr1, const float* __restrict__ wt1,
                 const float* __restrict__ wr2, const float* __restrict__ wt2,
                 unsigned short* __restrict__ Wp, int* __restrict__ bcursor) {
    int b = blockIdx.x;
    if (b < CVT_BLOCKS) {
        int i = b * 256 + threadIdx.x;       // N*DIM is an exact multiple
        X[i] = f2bf(x[i]);
    } else if (b == CVT_BLOCKS) {
        for (int i = threadIdx.x; i < NBUCK; i += 256) bcursor[i] = 0;
    } else {
        int id = (b - CVT_BLOCKS - 1) * 256 + threadIdx.x;   // < 3*32768
        int layer = id >> 15;
        int rem = id & 32767;
        int j  = rem & 7;
        int L  = (rem >> 3) & 63;
        int ct = (rem >> 9) & 7;
        int t  = rem >> 12;
        int k = t * 32 + (L >> 4) * 8 + j;
        int c = ct * 16 + (L & 15);
        const float* wr = (layer == 0) ? wr0 : (layer == 1) ? wr1 : wr2;
        const float* wt = (layer == 0) ? wt0 : (layer == 1) ? wt1 : wt2;
        float v = (k < 128) ? wr[k * 128 + c] : wt[(k - 128) * 128 + c];
        Wp[id] = f2bf(v);
    }
}

// Pass 1: bin edges by bucket (dst>>7) through LDS, contiguous runs to staging.
// 1024 threads (was 512): doubles resident-thread count of this
// parallelism-starved phase; scan logic widened to 16 waves.
__global__ __launch_bounds__(1024)
void partition_kernel(const int* __restrict__ src, const int* __restrict__ dst,
                      const float* __restrict__ ew,
                      int* __restrict__ bcursor, int2* __restrict__ bstage, int e) {
    __shared__ int2 stage[CHUNK];      // 16 KB
    __shared__ int cnt[NBUCK];
    __shared__ int lbase[NBUCK];
    __shared__ int gbase[NBUCK];
    __shared__ int wsum[16];
    const int tid = threadIdx.x;
    const int e0 = blockIdx.x * CHUNK;
    const int ecnt = min(CHUNK, e - e0);

    for (int i = tid; i < NBUCK; i += 1024) cnt[i] = 0;
    __syncthreads();
    for (int i = tid; i < ecnt; i += 1024)
        atomicAdd(&cnt[dst[e0 + i] >> 7], 1);
    __syncthreads();

    {
        int v = (tid < NBUCK) ? cnt[tid] : 0;
        int lane = tid & 63, wid = tid >> 6;
        int acc = v;
#pragma unroll
        for (int off = 1; off < 64; off <<= 1) {
            int t = __shfl_up(acc, off, 64);
            if (lane >= off) acc += t;
        }
        if (lane == 63) wsum[wid] = acc;
        __syncthreads();
        int wpref = 0;
        for (int w = 0; w < wid; ++w) wpref += wsum[w];
        int excl = wpref + acc - v;
        if (tid < NBUCK) {
            lbase[tid] = excl;
            gbase[tid] = atomicAdd(&bcursor[tid], v);
            cnt[tid] = 0;            // reuse as local cursor
        }
    }
    __syncthreads();

    for (int i = tid; i < ecnt; i += 1024) {
        int d = dst[e0 + i];
        int s = src[e0 + i];
        unsigned int hw = (unsigned int)__half_as_ushort(__float2half(ew[e0 + i]));
        int b = d >> 7;
        int pos = atomicAdd(&cnt[b], 1);
        stage[lbase[b] + pos] = make_int2((int)((hw << 16) | (unsigned int)s), d);
    }
    __syncthreads();

    for (int j = tid; j < ecnt; j += 1024) {
        int2 p = stage[j];
        int b = p.y >> 7;
        int gidx = b * BCAP + gbase[b] + (j - lbase[b]);
        bstage[gidx] = p;
    }
}

// Pass 2: per bucket (128 nodes, 391 blocks) — 512 threads (was 256) to raise
// resident-wave count; bucket-total scan now 1 entry/thread.
__global__ __launch_bounds__(512)
void bucket_fill_kernel(const int2* __restrict__ bstage, const int* __restrict__ bcursor,
                        int* __restrict__ row_start, unsigned int* __restrict__ perm4, int n) {
    __shared__ int cnt128[128];
    __shared__ int curs[128];
    __shared__ int wsum[8];
    __shared__ int sbase, scnt;
    const int tid = threadIdx.x;
    const int b = blockIdx.x;
    const int node0 = b << 7;
    const int lane = tid & 63, wid = tid >> 6;

    // exclusive prefix over 391 bucket totals, 1 entry per thread (512 >= 391)
    {
        int v = (tid < NBUCK) ? bcursor[tid] : 0;
        int acc = v;
#pragma unroll
        for (int off = 1; off < 64; off <<= 1) {
            int t = __shfl_up(acc, off, 64);
            if (lane >= off) acc += t;
        }
        if (lane == 63) wsum[wid] = acc;
        __syncthreads();
        int wpref = 0;
        for (int w = 0; w < wid; ++w) wpref += wsum[w];
        int excl = wpref + acc - v;
        if (tid == b) { sbase = excl; scnt = v; }
    }
    __syncthreads();
    const int cntb = scnt;
    const int base = sbase;
    const int2* sp = bstage + (size_t)b * BCAP;

    if (tid < 128) cnt128[tid] = 0;
    __syncthreads();
    for (int i = tid; i < cntb; i += 512)
        atomicAdd(&cnt128[sp[i].y & 127], 1);
    __syncthreads();

    // scan 128 per-node counts (first 2 waves carry data)
    int v = (tid < 128) ? cnt128[tid] : 0;
    int acc = v;
#pragma unroll
    for (int off = 1; off < 64; off <<= 1) {
        int t = __shfl_up(acc, off, 64);
        if (lane >= off) acc += t;
    }
    if (lane == 63) wsum[wid] = acc;
    __syncthreads();
    int wpref = 0;
    for (int w = 0; w < wid; ++w) wpref += wsum[w];
    int excl = wpref + acc - v;
    if (tid < 128) {
        int node = node0 + tid;
        if (node <= n) row_start[node] = base + excl;
        curs[tid] = excl;
    }
    __syncthreads();

    for (int i = tid; i < cntb; i += 512) {
        int2 p = sp[i];
        int pos = atomicAdd(&curs[p.y & 127], 1);
        perm4[base + pos] = (unsigned int)p.x;
    }
}

// ---------------------------------------------------------------------------
// Fused layer v5: block = 16 rows, 256 threads (4 waves), ONE barrier.
// Phase 1: lane-group g (16 lanes) OWNS node nodeBase+g — one flat edge loop,
//          no cross-group shuffle reduce, no serial per-node sections, no
//          bounds checks (grid is exactly N/16). 4 edges in flight per iter.
// Phase 2: all waves share the 16 LDS rows; wave w computes cols [32w,32w+32).
__global__ __launch_bounds__(256, 8)
void fused_layer(const unsigned short* __restrict__ h, const int* __restrict__ row_start,
                 const unsigned int* __restrict__ perm4, const unsigned short* __restrict__ Wp,
                 const float* __restrict__ bias, float* __restrict__ outF,
                 unsigned short* __restrict__ outB, int relu) {
    __shared__ unsigned short Gs[16 * LDSROW];   // 4.25 KB
    const int tid  = threadIdx.x;
    const int lane = tid & 63;
    const int wid  = tid >> 6;
    const int g  = lane >> 4;      // node owner (phase1) / k-offset quad (phase2)
    const int sl = lane & 15;      // col-chunk (phase1) / A-row (phase2)
    const int rowT = blockIdx.x * 16;
    const int nodeBase = rowT + wid * 4;

    // row_start window for this wave's 4 nodes (one load, distribute by shfl)
    int rs = 0;
    if (lane < 5) rs = row_start[nodeBase + lane];
    const int beg = __shfl(rs, g, 64);
    const int end = __shfl(rs, g + 1, 64);

    // ---- phase 1: group g aggregates node nodeBase+g, dims [8sl, 8sl+8) ----
    floatx2 ac[4];
#pragma unroll
    for (int k = 0; k < 4; ++k) ac[k] = (floatx2){0.f, 0.f};
    const unsigned short* hp = h + sl * 8;
    for (int t = beg; t < end; t += 4) {
        unsigned int p0 = perm4[t];                          // t < end always
        unsigned int p1 = (t + 1 < end) ? perm4[t + 1] : 0;  // p=0 -> src 0, w=+0
        unsigned int p2 = (t + 2 < end) ? perm4[t + 2] : 0;
        unsigned int p3 = (t + 3 < end) ? perm4[t + 3] : 0;
        uint4 v0 = *(const uint4*)(hp + (size_t)(p0 & 0xFFFF) * DIM);
        uint4 v1 = *(const uint4*)(hp + (size_t)(p1 & 0xFFFF) * DIM);
        uint4 v2 = *(const uint4*)(hp + (size_t)(p2 & 0xFFFF) * DIM);
        uint4 v3 = *(const uint4*)(hp + (size_t)(p3 & 0xFFFF) * DIM);
        float w0 = __half2float(__ushort_as_half((unsigned short)(p0 >> 16)));
        float w1 = __half2float(__ushort_as_half((unsigned short)(p1 >> 16)));
        float w2 = __half2float(__ushort_as_half((unsigned short)(p2 >> 16)));
        float w3 = __half2float(__ushort_as_half((unsigned short)(p3 >> 16)));
        floatx2 W0 = (floatx2){w0, w0}, W1 = (floatx2){w1, w1};
        floatx2 W2 = (floatx2){w2, w2}, W3 = (floatx2){w3, w3};
        ac[0] += W0 * bf2x2(v0.x); ac[1] += W0 * bf2x2(v0.y);
        ac[2] += W0 * bf2x2(v0.z); ac[3] += W0 * bf2x2(v0.w);
        ac[0] += W1 * bf2x2(v1.x); ac[1] += W1 * bf2x2(v1.y);
        ac[2] += W1 * bf2x2(v1.z); ac[3] += W1 * bf2x2(v1.w);
        ac[0] += W2 * bf2x2(v2.x); ac[1] += W2 * bf2x2(v2.y);
        ac[2] += W2 * bf2x2(v2.z); ac[3] += W2 * bf2x2(v2.w);
        ac[0] += W3 * bf2x2(v3.x); ac[1] += W3 * bf2x2(v3.y);
        ac[2] += W3 * bf2x2(v3.z); ac[3] += W3 * bf2x2(v3.w);
    }
    // group g's 16 lanes hold the full 128-dim aggregate of its node: no
    // cross-lane reduce needed; all 64 lanes store (4 rows per wave at once).
    {
        uint4 r;
        r.x = (unsigned int)f2bf(ac[0].x) | ((unsigned int)f2bf(ac[0].y) << 16);
        r.y = (unsigned int)f2bf(ac[1].x) | ((unsigned int)f2bf(ac[1].y) << 16);
        r.z = (unsigned int)f2bf(ac[2].x) | ((unsigned int)f2bf(ac[2].y) << 16);
        r.w = (unsigned int)f2bf(ac[3].x) | ((unsigned int)f2bf(ac[3].y) << 16);
        *(uint4*)(&Gs[(wid * 4 + g) * LDSROW + sl * 8]) = r;
    }
    __syncthreads();   // waves now read rows written by other waves

    // ---- phase 2: wave w -> 16 rows x cols [32w, 32w+32) ----
    floatx4 acc2[2];
#pragma unroll
    for (int ct = 0; ct < 2; ++ct) acc2[ct] = (floatx4){0.f, 0.f, 0.f, 0.f};

    const int rr = rowT + sl;          // grid exact: always < N
    const int ko = g * 8;
#pragma unroll
    for (int t = 0; t < 8; ++t) {
        shortx8 a;
        if (t < 4)
            a = *(const shortx8*)(&Gs[sl * LDSROW + t * 32 + ko]);
        else
            a = *(const shortx8*)(h + (size_t)rr * DIM + (t - 4) * 32 + ko);
        const unsigned short* wp = Wp + (size_t)t * 4096 + (wid * 2) * 512 + lane * 8;
#pragma unroll
        for (int ct = 0; ct < 2; ++ct) {
            shortx8 b = *(const shortx8*)(wp + ct * 512);
            acc2[ct] = __builtin_amdgcn_mfma_f32_16x16x32_bf16(a, b, acc2[ct], 0, 0, 0);
        }
    }

#pragma unroll
    for (int ct = 0; ct < 2; ++ct) {
        int col = wid * 32 + ct * 16 + sl;
        float bv = bias[col];
#pragma unroll
        for (int i = 0; i < 4; ++i) {
            int row = rowT + g * 4 + i;
            float v = acc2[ct][i] + bv;
            if (relu) v = fmaxf(v, 0.f);
            if (outF) outF[(size_t)row * DIM + col] = v;
            else      outB[(size_t)row * DIM + col] = f2bf(v);
        }
    }
}

extern "C" void kernel_launch(void* const* d_in, const int* in_sizes, int n_in,
                              void* d_out, int out_size, void* d_ws, size_t ws_size,
                              hipStream_t stream) {
    const int N = N_NODES, E = N_EDGES;

    const float* x   = (const float*)d_in[0];
    const int*   ei  = (const int*)d_in[1];
    const float* ea  = (const float*)d_in[2];
    const float* wr0 = (const float*)d_in[3];
    const float* br0 = (const float*)d_in[4];
    const float* wt0 = (const float*)d_in[5];
    const float* wr1 = (const float*)d_in[6];
    const float* br1 = (const float*)d_in[7];
    const float* wt1 = (const float*)d_in[8];
    const float* wr2 = (const float*)d_in[9];
    const float* br2 = (const float*)d_in[10];
    const float* wt2 = (const float*)d_in[11];
    const int* srcI = ei;
    const int* dstI = ei + E;
    float* out = (float*)d_out;

    // workspace layout (bstage first for 8B alignment)
    int2* bstage = (int2*)d_ws;                              // NBUCK*BCAP int2 (8.8MB)
    unsigned short* X  = (unsigned short*)(bstage + (size_t)NBUCK * BCAP);  // N*128 bf16
    unsigned short* H1 = X + (size_t)N * DIM;                // N*128 bf16
    unsigned short* H2 = H1 + (size_t)N * DIM;               // N*128 bf16
    unsigned short* Wp = H2 + (size_t)N * DIM;               // 3*32768 bf16
    unsigned int* perm4 = (unsigned int*)(Wp + 3 * 32768);   // E u32
    int* bcursor = (int*)(perm4 + E);                        // NBUCK i32
    int* rowst   = bcursor + NBUCK;                          // N+1 i32

    // prep (cvt + zero + pack) and CSR build via binned counting sort
    prep_kernel<<<CVT_BLOCKS + 1 + 384, 256, 0, stream>>>(x, X, wr0, wt0, wr1, wt1, wr2, wt2, Wp, bcursor);
    partition_kernel<<<(E + CHUNK - 1) / CHUNK, 1024, 0, stream>>>(srcI, dstI, ea, bcursor, bstage, E);
    bucket_fill_kernel<<<NBUCK, 512, 0, stream>>>(bstage, bcursor, rowst, perm4, N);

    const int fusedGrid = N / 16;            // 3125 blocks, 16 rows each (exact)

    // ping-pong h buffers: gathers read prev layer, writes go to a new buffer
    fused_layer<<<fusedGrid, 256, 0, stream>>>(X,  rowst, perm4, Wp,         br0, nullptr, H1, 1);
    fused_layer<<<fusedGrid, 256, 0, stream>>>(H1, rowst, perm4, Wp + 32768, br1, nullptr, H2, 1);
    fused_layer<<<fusedGrid, 256, 0, stream>>>(H2, rowst, perm4, Wp + 65536, br2, out, nullptr, 0);
}

// Round 2
// 231.942 us; speedup vs baseline: 1.0519x; 1.0177x over previous
//
#include <hip/hip_runtime.h>
#include <hip/hip_bf16.h>
#include <hip/hip_fp16.h>

#define N_NODES 50000
#define N_EDGES 800000
#define DIM 128

#define NBUCK 391      // ceil(N/128) buckets of 128 consecutive dst nodes
#define BCAP  2816     // per-bucket staging capacity (mean 2046, sigma 45 -> +17 sigma)
#define CHUNK 2048     // edges per partition block (391 blocks)

#define CVT_BLOCKS 25000   // 25000*256 == N_NODES*DIM exactly

#define LDSROW 136     // Gs row stride in shorts (272 B: 2-way bank alias = free)

typedef float floatx4 __attribute__((ext_vector_type(4)));
typedef float floatx2 __attribute__((ext_vector_type(2)));
typedef short shortx8 __attribute__((ext_vector_type(8)));

__device__ __forceinline__ unsigned short f2bf(float f) {
    union { float f; unsigned int u; } c; c.f = f;
    unsigned int u = c.u;
    unsigned int r = (u + 0x7FFFu + ((u >> 16) & 1u)) >> 16;
    return (unsigned short)r;
}
// unpack u32 (2 bf16) -> packed float2 (feeds v_pk_fma_f32)
__device__ __forceinline__ floatx2 bf2x2(unsigned int p) {
    union { unsigned int u; float f; } lo, hi;
    lo.u = p << 16; hi.u = p & 0xFFFF0000u;
    return (floatx2){lo.f, hi.f};
}

// ---------------------------------------------------------------------------
// prep: fused  x->bf16 convert | zero bcursor | weight pack
__global__ __launch_bounds__(256)
void prep_kernel(const float* __restrict__ x, unsigned short* __restrict__ X,
                 const float* __restrict__ wr0, const float* __restrict__ wt0,
                 const float* __restrict__ wr1, const float* __restrict__ wt1,
                 const float* __restrict__ wr2, const float* __restrict__ wt2,
                 unsigned short* __restrict__ Wp, int* __restrict__ bcursor) {
    int b = blockIdx.x;
    if (b < CVT_BLOCKS) {
        int i = b * 256 + threadIdx.x;       // N*DIM is an exact multiple
        X[i] = f2bf(x[i]);
    } else if (b == CVT_BLOCKS) {
        for (int i = threadIdx.x; i < NBUCK; i += 256) bcursor[i] = 0;
    } else {
        int id = (b - CVT_BLOCKS - 1) * 256 + threadIdx.x;   // < 3*32768
        int layer = id >> 15;
        int rem = id & 32767;
        int j  = rem & 7;
        int L  = (rem >> 3) & 63;
        int ct = (rem >> 9) & 7;
        int t  = rem >> 12;
        int k = t * 32 + (L >> 4) * 8 + j;
        int c = ct * 16 + (L & 15);
        const float* wr = (layer == 0) ? wr0 : (layer == 1) ? wr1 : wr2;
        const float* wt = (layer == 0) ? wt0 : (layer == 1) ? wt1 : wt2;
        float v = (k < 128) ? wr[k * 128 + c] : wt[(k - 128) * 128 + c];
        Wp[id] = f2bf(v);
    }
}

// Pass 1: bin edges by bucket (dst>>7) through LDS, contiguous runs to staging.
__global__ __launch_bounds__(1024)
void partition_kernel(const int* __restrict__ src, const int* __restrict__ dst,
                      const float* __restrict__ ew,
                      int* __restrict__ bcursor, int2* __restrict__ bstage, int e) {
    __shared__ int2 stage[CHUNK];      // 16 KB
    __shared__ int cnt[NBUCK];
    __shared__ int lbase[NBUCK];
    __shared__ int gbase[NBUCK];
    __shared__ int wsum[16];
    const int tid = threadIdx.x;
    const int e0 = blockIdx.x * CHUNK;
    const int ecnt = min(CHUNK, e - e0);

    for (int i = tid; i < NBUCK; i += 1024) cnt[i] = 0;
    __syncthreads();
    for (int i = tid; i < ecnt; i += 1024)
        atomicAdd(&cnt[dst[e0 + i] >> 7], 1);
    __syncthreads();

    {
        int v = (tid < NBUCK) ? cnt[tid] : 0;
        int lane = tid & 63, wid = tid >> 6;
        int acc = v;
#pragma unroll
        for (int off = 1; off < 64; off <<= 1) {
            int t = __shfl_up(acc, off, 64);
            if (lane >= off) acc += t;
        }
        if (lane == 63) wsum[wid] = acc;
        __syncthreads();
        int wpref = 0;
        for (int w = 0; w < wid; ++w) wpref += wsum[w];
        int excl = wpref + acc - v;
        if (tid < NBUCK) {
            lbase[tid] = excl;
            gbase[tid] = atomicAdd(&bcursor[tid], v);
            cnt[tid] = 0;            // reuse as local cursor
        }
    }
    __syncthreads();

    for (int i = tid; i < ecnt; i += 1024) {
        int d = dst[e0 + i];
        int s = src[e0 + i];
        unsigned int hw = (unsigned int)__half_as_ushort(__float2half(ew[e0 + i]));
        int b = d >> 7;
        int pos = atomicAdd(&cnt[b], 1);
        stage[lbase[b] + pos] = make_int2((int)((hw << 16) | (unsigned int)s), d);
    }
    __syncthreads();

    for (int j = tid; j < ecnt; j += 1024) {
        int2 p = stage[j];
        int b = p.y >> 7;
        int gidx = b * BCAP + gbase[b] + (j - lbase[b]);
        bstage[gidx] = p;
    }
}

// Pass 2: per bucket (128 nodes, 391 blocks), 512 threads.
__global__ __launch_bounds__(512)
void bucket_fill_kernel(const int2* __restrict__ bstage, const int* __restrict__ bcursor,
                        int* __restrict__ row_start, unsigned int* __restrict__ perm4, int n) {
    __shared__ int cnt128[128];
    __shared__ int curs[128];
    __shared__ int wsum[8];
    __shared__ int sbase, scnt;
    const int tid = threadIdx.x;
    const int b = blockIdx.x;
    const int node0 = b << 7;
    const int lane = tid & 63, wid = tid >> 6;

    // exclusive prefix over 391 bucket totals, 1 entry per thread (512 >= 391)
    {
        int v = (tid < NBUCK) ? bcursor[tid] : 0;
        int acc = v;
#pragma unroll
        for (int off = 1; off < 64; off <<= 1) {
            int t = __shfl_up(acc, off, 64);
            if (lane >= off) acc += t;
        }
        if (lane == 63) wsum[wid] = acc;
        __syncthreads();
        int wpref = 0;
        for (int w = 0; w < wid; ++w) wpref += wsum[w];
        int excl = wpref + acc - v;
        if (tid == b) { sbase = excl; scnt = v; }
    }
    __syncthreads();
    const int cntb = scnt;
    const int base = sbase;
    const int2* sp = bstage + (size_t)b * BCAP;

    if (tid < 128) cnt128[tid] = 0;
    __syncthreads();
    for (int i = tid; i < cntb; i += 512)
        atomicAdd(&cnt128[sp[i].y & 127], 1);
    __syncthreads();

    // scan 128 per-node counts (first 2 waves carry data)
    int v = (tid < 128) ? cnt128[tid] : 0;
    int acc = v;
#pragma unroll
    for (int off = 1; off < 64; off <<= 1) {
        int t = __shfl_up(acc, off, 64);
        if (lane >= off) acc += t;
    }
    if (lane == 63) wsum[wid] = acc;
    __syncthreads();
    int wpref = 0;
    for (int w = 0; w < wid; ++w) wpref += wsum[w];
    int excl = wpref + acc - v;
    if (tid < 128) {
        int node = node0 + tid;
        if (node <= n) row_start[node] = base + excl;
        curs[tid] = excl;
    }
    __syncthreads();

    for (int i = tid; i < cntb; i += 512) {
        int2 p = sp[i];
        int pos = atomicAdd(&curs[p.y & 127], 1);
        perm4[base + pos] = (unsigned int)p.x;
    }
}

// ---------------------------------------------------------------------------
// Fused layer v6: block = 16 rows, 256 threads (4 waves), ONE barrier.
// Phase 1: lane-group g owns node nodeBase+g; edge loop is 2-deep software-
//          pipelined (issue quad t+1's perm+gather, accumulate quad t) so each
//          wave keeps 4 gathers in flight while computing.
// Phase 1.5: root-GEMM half of the output (reads only h + Wp, no LDS dep) runs
//          BEFORE the barrier — fast waves do MFMA while stragglers gather.
// Phase 2: aggregate-GEMM half from LDS after the barrier.
#define ACCQ(p, v) do { \
    float w_ = __half2float(__ushort_as_half((unsigned short)((p) >> 16))); \
    floatx2 W_ = (floatx2){w_, w_}; \
    ac[0] += W_ * bf2x2((v).x); ac[1] += W_ * bf2x2((v).y); \
    ac[2] += W_ * bf2x2((v).z); ac[3] += W_ * bf2x2((v).w); \
} while (0)

__global__ __launch_bounds__(256, 6)
void fused_layer(const unsigned short* __restrict__ h, const int* __restrict__ row_start,
                 const unsigned int* __restrict__ perm4, const unsigned short* __restrict__ Wp,
                 const float* __restrict__ bias, float* __restrict__ outF,
                 unsigned short* __restrict__ outB, int relu) {
    __shared__ unsigned short Gs[16 * LDSROW];   // 4.25 KB
    const int tid  = threadIdx.x;
    const int lane = tid & 63;
    const int wid  = tid >> 6;
    const int g  = lane >> 4;      // node owner (phase1) / k-offset quad (phase2)
    const int sl = lane & 15;      // col-chunk (phase1) / A-row (phase2)
    const int rowT = blockIdx.x * 16;
    const int nodeBase = rowT + wid * 4;

    // row_start window for this wave's 4 nodes (one load, distribute by shfl)
    int rs = 0;
    if (lane < 5) rs = row_start[nodeBase + lane];
    const int beg = __shfl(rs, g, 64);
    const int end = __shfl(rs, g + 1, 64);

    // ---- phase 1: group g aggregates node nodeBase+g, dims [8sl, 8sl+8) ----
    floatx2 ac[4];
#pragma unroll
    for (int k = 0; k < 4; ++k) ac[k] = (floatx2){0.f, 0.f};
    const unsigned short* hp = h + sl * 8;
    const bool any = beg < end;
    unsigned int pA0 = 0, pA1 = 0, pA2 = 0, pA3 = 0;
    uint4 vA0 = {}, vA1 = {}, vA2 = {}, vA3 = {};
    int t = beg;
    if (any) {
        pA0 = perm4[t];
        pA1 = (t + 1 < end) ? perm4[t + 1] : 0u;   // p=0 -> src 0, w=+0
        pA2 = (t + 2 < end) ? perm4[t + 2] : 0u;
        pA3 = (t + 3 < end) ? perm4[t + 3] : 0u;
        vA0 = *(const uint4*)(hp + (size_t)(pA0 & 0xFFFFu) * DIM);
        vA1 = *(const uint4*)(hp + (size_t)(pA1 & 0xFFFFu) * DIM);
        vA2 = *(const uint4*)(hp + (size_t)(pA2 & 0xFFFFu) * DIM);
        vA3 = *(const uint4*)(hp + (size_t)(pA3 & 0xFFFFu) * DIM);
    }
    for (; t + 4 < end; t += 4) {
        unsigned int pB0 = perm4[t + 4];
        unsigned int pB1 = (t + 5 < end) ? perm4[t + 5] : 0u;
        unsigned int pB2 = (t + 6 < end) ? perm4[t + 6] : 0u;
        unsigned int pB3 = (t + 7 < end) ? perm4[t + 7] : 0u;
        uint4 vB0 = *(const uint4*)(hp + (size_t)(pB0 & 0xFFFFu) * DIM);
        uint4 vB1 = *(const uint4*)(hp + (size_t)(pB1 & 0xFFFFu) * DIM);
        uint4 vB2 = *(const uint4*)(hp + (size_t)(pB2 & 0xFFFFu) * DIM);
        uint4 vB3 = *(const uint4*)(hp + (size_t)(pB3 & 0xFFFFu) * DIM);
        ACCQ(pA0, vA0); ACCQ(pA1, vA1); ACCQ(pA2, vA2); ACCQ(pA3, vA3);
        pA0 = pB0; pA1 = pB1; pA2 = pB2; pA3 = pB3;
        vA0 = vB0; vA1 = vB1; vA2 = vB2; vA3 = vB3;
    }
    if (any) { ACCQ(pA0, vA0); ACCQ(pA1, vA1); ACCQ(pA2, vA2); ACCQ(pA3, vA3); }

    // group g's 16 lanes hold the full 128-dim aggregate of its node
    {
        uint4 r;
        r.x = (unsigned int)f2bf(ac[0].x) | ((unsigned int)f2bf(ac[0].y) << 16);
        r.y = (unsigned int)f2bf(ac[1].x) | ((unsigned int)f2bf(ac[1].y) << 16);
        r.z = (unsigned int)f2bf(ac[2].x) | ((unsigned int)f2bf(ac[2].y) << 16);
        r.w = (unsigned int)f2bf(ac[3].x) | ((unsigned int)f2bf(ac[3].y) << 16);
        *(uint4*)(&Gs[(wid * 4 + g) * LDSROW + sl * 8]) = r;
    }

    // ---- phase 1.5: root-GEMM half (h rows, no LDS dependency) ----
    floatx4 acc2[2];
#pragma unroll
    for (int ct = 0; ct < 2; ++ct) acc2[ct] = (floatx4){0.f, 0.f, 0.f, 0.f};
    const int rr = rowT + sl;          // grid exact: always < N
    const int ko = g * 8;
#pragma unroll
    for (int t2 = 4; t2 < 8; ++t2) {
        shortx8 a = *(const shortx8*)(h + (size_t)rr * DIM + (t2 - 4) * 32 + ko);
        const unsigned short* wp = Wp + (size_t)t2 * 4096 + (wid * 2) * 512 + lane * 8;
#pragma unroll
        for (int ct = 0; ct < 2; ++ct) {
            shortx8 b = *(const shortx8*)(wp + ct * 512);
            acc2[ct] = __builtin_amdgcn_mfma_f32_16x16x32_bf16(a, b, acc2[ct], 0, 0, 0);
        }
    }

    __syncthreads();   // waves now read rows written by other waves

    // ---- phase 2: aggregate-GEMM half from LDS ----
#pragma unroll
    for (int t2 = 0; t2 < 4; ++t2) {
        shortx8 a = *(const shortx8*)(&Gs[sl * LDSROW + t2 * 32 + ko]);
        const unsigned short* wp = Wp + (size_t)t2 * 4096 + (wid * 2) * 512 + lane * 8;
#pragma unroll
        for (int ct = 0; ct < 2; ++ct) {
            shortx8 b = *(const shortx8*)(wp + ct * 512);
            acc2[ct] = __builtin_amdgcn_mfma_f32_16x16x32_bf16(a, b, acc2[ct], 0, 0, 0);
        }
    }

#pragma unroll
    for (int ct = 0; ct < 2; ++ct) {
        int col = wid * 32 + ct * 16 + sl;
        float bv = bias[col];
#pragma unroll
        for (int i = 0; i < 4; ++i) {
            int row = rowT + g * 4 + i;
            float v = acc2[ct][i] + bv;
            if (relu) v = fmaxf(v, 0.f);
            if (outF) outF[(size_t)row * DIM + col] = v;
            else      outB[(size_t)row * DIM + col] = f2bf(v);
        }
    }
}

extern "C" void kernel_launch(void* const* d_in, const int* in_sizes, int n_in,
                              void* d_out, int out_size, void* d_ws, size_t ws_size,
                              hipStream_t stream) {
    const int N = N_NODES, E = N_EDGES;

    const float* x   = (const float*)d_in[0];
    const int*   ei  = (const int*)d_in[1];
    const float* ea  = (const float*)d_in[2];
    const float* wr0 = (const float*)d_in[3];
    const float* br0 = (const float*)d_in[4];
    const float* wt0 = (const float*)d_in[5];
    const float* wr1 = (const float*)d_in[6];
    const float* br1 = (const float*)d_in[7];
    const float* wt1 = (const float*)d_in[8];
    const float* wr2 = (const float*)d_in[9];
    const float* br2 = (const float*)d_in[10];
    const float* wt2 = (const float*)d_in[11];
    const int* srcI = ei;
    const int* dstI = ei + E;
    float* out = (float*)d_out;

    // workspace layout (bstage first for 8B alignment)
    int2* bstage = (int2*)d_ws;                              // NBUCK*BCAP int2 (8.8MB)
    unsigned short* X  = (unsigned short*)(bstage + (size_t)NBUCK * BCAP);  // N*128 bf16
    unsigned short* H1 = X + (size_t)N * DIM;                // N*128 bf16
    unsigned short* H2 = H1 + (size_t)N * DIM;               // N*128 bf16
    unsigned short* Wp = H2 + (size_t)N * DIM;               // 3*32768 bf16
    unsigned int* perm4 = (unsigned int*)(Wp + 3 * 32768);   // E u32
    int* bcursor = (int*)(perm4 + E);                        // NBUCK i32
    int* rowst   = bcursor + NBUCK;                          // N+1 i32

    // prep (cvt + zero + pack) and CSR build via binned counting sort
    prep_kernel<<<CVT_BLOCKS + 1 + 384, 256, 0, stream>>>(x, X, wr0, wt0, wr1, wt1, wr2, wt2, Wp, bcursor);
    partition_kernel<<<(E + CHUNK - 1) / CHUNK, 1024, 0, stream>>>(srcI, dstI, ea, bcursor, bstage, E);
    bucket_fill_kernel<<<NBUCK, 512, 0, stream>>>(bstage, bcursor, rowst, perm4, N);

    const int fusedGrid = N / 16;            // 3125 blocks, 16 rows each (exact)

    // ping-pong h buffers: gathers read prev layer, writes go to a new buffer
    fused_layer<<<fusedGrid, 256, 0, stream>>>(X,  rowst, perm4, Wp,         br0, nullptr, H1, 1);
    fused_layer<<<fusedGrid, 256, 0, stream>>>(H1, rowst, perm4, Wp + 32768, br1, nullptr, H2, 1);
    fused_layer<<<fusedGrid, 256, 0, stream>>>(H2, rowst, perm4, Wp + 65536, br2, out, nullptr, 0);
}

// Round 3
// 224.609 us; speedup vs baseline: 1.0863x; 1.0326x over previous
//
#include <hip/hip_runtime.h>
#include <hip/hip_bf16.h>
#include <hip/hip_fp16.h>

#define N_NODES 50000
#define N_EDGES 800000
#define DIM 128

#define NBUCK 391      // ceil(N/128) buckets of 128 consecutive dst nodes
#define BCAP  2816     // per-bucket staging capacity (mean 2046, sigma 45 -> +17 sigma)
#define CHUNK 2048     // edges per partition block (391 blocks)

#define CVT_BLOCKS 12500   // 12500*256*2 == N_NODES*DIM exactly (2 elems/thread)

#define LDSROW 136     // Gs row stride in shorts (272 B: 2-way bank alias = free)

typedef float floatx4 __attribute__((ext_vector_type(4)));
typedef float floatx2 __attribute__((ext_vector_type(2)));
typedef short shortx8 __attribute__((ext_vector_type(8)));

__device__ __forceinline__ unsigned short f2bf(float f) {
    union { float f; unsigned int u; } c; c.f = f;
    unsigned int u = c.u;
    unsigned int r = (u + 0x7FFFu + ((u >> 16) & 1u)) >> 16;
    return (unsigned short)r;
}
__device__ __forceinline__ unsigned char f2fp8(float f) {
    unsigned int p = __builtin_amdgcn_cvt_pk_fp8_f32(f, f, 0u, false);
    return (unsigned char)(p & 0xFFu);
}

// ---------------------------------------------------------------------------
// prep: fused  x->bf16+fp8 convert | zero bcursor | weight pack
__global__ __launch_bounds__(256)
void prep_kernel(const float* __restrict__ x, unsigned short* __restrict__ X,
                 unsigned char* __restrict__ X8,
                 const float* __restrict__ wr0, const float* __restrict__ wt0,
                 const float* __restrict__ wr1, const float* __restrict__ wt1,
                 const float* __restrict__ wr2, const float* __restrict__ wt2,
                 unsigned short* __restrict__ Wp, int* __restrict__ bcursor) {
    int b = blockIdx.x;
    if (b < CVT_BLOCKS) {
        int i = (b * 256 + threadIdx.x) * 2;   // N*DIM exact multiple of 512
        float2 xv = *(const float2*)(x + i);
        *(unsigned int*)(X + i) =
            (unsigned int)f2bf(xv.x) | ((unsigned int)f2bf(xv.y) << 16);
        unsigned int p8 = __builtin_amdgcn_cvt_pk_fp8_f32(xv.x, xv.y, 0u, false);
        *(unsigned short*)(X8 + i) = (unsigned short)(p8 & 0xFFFFu);
    } else if (b == CVT_BLOCKS) {
        for (int i = threadIdx.x; i < NBUCK; i += 256) bcursor[i] = 0;
    } else {
        int id = (b - CVT_BLOCKS - 1) * 256 + threadIdx.x;   // < 3*32768
        int layer = id >> 15;
        int rem = id & 32767;
        int j  = rem & 7;
        int L  = (rem >> 3) & 63;
        int ct = (rem >> 9) & 7;
        int t  = rem >> 12;
        int k = t * 32 + (L >> 4) * 8 + j;
        int c = ct * 16 + (L & 15);
        const float* wr = (layer == 0) ? wr0 : (layer == 1) ? wr1 : wr2;
        const float* wt = (layer == 0) ? wt0 : (layer == 1) ? wt1 : wt2;
        float v = (k < 128) ? wr[k * 128 + c] : wt[(k - 128) * 128 + c];
        Wp[id] = f2bf(v);
    }
}

// Pass 1: bin edges by bucket (dst>>7) through LDS, contiguous runs to staging.
__global__ __launch_bounds__(1024)
void partition_kernel(const int* __restrict__ src, const int* __restrict__ dst,
                      const float* __restrict__ ew,
                      int* __restrict__ bcursor, int2* __restrict__ bstage, int e) {
    __shared__ int2 stage[CHUNK];      // 16 KB
    __shared__ int cnt[NBUCK];
    __shared__ int lbase[NBUCK];
    __shared__ int gbase[NBUCK];
    __shared__ int wsum[16];
    const int tid = threadIdx.x;
    const int e0 = blockIdx.x * CHUNK;
    const int ecnt = min(CHUNK, e - e0);

    for (int i = tid; i < NBUCK; i += 1024) cnt[i] = 0;
    __syncthreads();
    for (int i = tid; i < ecnt; i += 1024)
        atomicAdd(&cnt[dst[e0 + i] >> 7], 1);
    __syncthreads();

    {
        int v = (tid < NBUCK) ? cnt[tid] : 0;
        int lane = tid & 63, wid = tid >> 6;
        int acc = v;
#pragma unroll
        for (int off = 1; off < 64; off <<= 1) {
            int t = __shfl_up(acc, off, 64);
            if (lane >= off) acc += t;
        }
        if (lane == 63) wsum[wid] = acc;
        __syncthreads();
        int wpref = 0;
        for (int w = 0; w < wid; ++w) wpref += wsum[w];
        int excl = wpref + acc - v;
        if (tid < NBUCK) {
            lbase[tid] = excl;
            gbase[tid] = atomicAdd(&bcursor[tid], v);
            cnt[tid] = 0;            // reuse as local cursor
        }
    }
    __syncthreads();

    for (int i = tid; i < ecnt; i += 1024) {
        int d = dst[e0 + i];
        int s = src[e0 + i];
        unsigned int hw = (unsigned int)__half_as_ushort(__float2half(ew[e0 + i]));
        int b = d >> 7;
        int pos = atomicAdd(&cnt[b], 1);
        stage[lbase[b] + pos] = make_int2((int)((hw << 16) | (unsigned int)s), d);
    }
    __syncthreads();

    for (int j = tid; j < ecnt; j += 1024) {
        int2 p = stage[j];
        int b = p.y >> 7;
        int gidx = b * BCAP + gbase[b] + (j - lbase[b]);
        bstage[gidx] = p;
    }
}

// Pass 2: per bucket (128 nodes, 391 blocks), 512 threads.
__global__ __launch_bounds__(512)
void bucket_fill_kernel(const int2* __restrict__ bstage, const int* __restrict__ bcursor,
                        int* __restrict__ row_start, unsigned int* __restrict__ perm4, int n) {
    __shared__ int cnt128[128];
    __shared__ int curs[128];
    __shared__ int wsum[8];
    __shared__ int sbase, scnt;
    const int tid = threadIdx.x;
    const int b = blockIdx.x;
    const int node0 = b << 7;
    const int lane = tid & 63, wid = tid >> 6;

    // exclusive prefix over 391 bucket totals, 1 entry per thread (512 >= 391)
    {
        int v = (tid < NBUCK) ? bcursor[tid] : 0;
        int acc = v;
#pragma unroll
        for (int off = 1; off < 64; off <<= 1) {
            int t = __shfl_up(acc, off, 64);
            if (lane >= off) acc += t;
        }
        if (lane == 63) wsum[wid] = acc;
        __syncthreads();
        int wpref = 0;
        for (int w = 0; w < wid; ++w) wpref += wsum[w];
        int excl = wpref + acc - v;
        if (tid == b) { sbase = excl; scnt = v; }
    }
    __syncthreads();
    const int cntb = scnt;
    const int base = sbase;
    const int2* sp = bstage + (size_t)b * BCAP;

    if (tid < 128) cnt128[tid] = 0;
    __syncthreads();
    for (int i = tid; i < cntb; i += 512)
        atomicAdd(&cnt128[sp[i].y & 127], 1);
    __syncthreads();

    // scan 128 per-node counts (first 2 waves carry data)
    int v = (tid < 128) ? cnt128[tid] : 0;
    int acc = v;
#pragma unroll
    for (int off = 1; off < 64; off <<= 1) {
        int t = __shfl_up(acc, off, 64);
        if (lane >= off) acc += t;
    }
    if (lane == 63) wsum[wid] = acc;
    __syncthreads();
    int wpref = 0;
    for (int w = 0; w < wid; ++w) wpref += wsum[w];
    int excl = wpref + acc - v;
    if (tid < 128) {
        int node = node0 + tid;
        if (node <= n) row_start[node] = base + excl;
        curs[tid] = excl;
    }
    __syncthreads();

    for (int i = tid; i < cntb; i += 512) {
        int2 p = sp[i];
        int pos = atomicAdd(&curs[p.y & 127], 1);
        perm4[base + pos] = (unsigned int)p.x;
    }
}

// ---------------------------------------------------------------------------
// Fused layer v7: fp8 gather path (halves the L2-miss traffic that bounds
// phase 1). Gathers read h8 (fp8 e4m3, 128 B/row) and decode with
// v_cvt_pk_f32_fp8; accumulation stays f32; root path + MFMA stay bf16.
// Phase 1: lane-group g owns node nodeBase+g; 2-deep software pipeline.
// Phase 1.5: root-GEMM half before the barrier (no LDS dep).
// Phase 2: aggregate-GEMM half from LDS.
#define ACCQ(p, v) do { \
    float w_ = __half2float(__ushort_as_half((unsigned short)((p) >> 16))); \
    floatx2 W_ = (floatx2){w_, w_}; \
    floatx2 f0_ = __builtin_amdgcn_cvt_pk_f32_fp8((v).x, false); \
    floatx2 f1_ = __builtin_amdgcn_cvt_pk_f32_fp8((v).x, true);  \
    floatx2 f2_ = __builtin_amdgcn_cvt_pk_f32_fp8((v).y, false); \
    floatx2 f3_ = __builtin_amdgcn_cvt_pk_f32_fp8((v).y, true);  \
    ac[0] += W_ * f0_; ac[1] += W_ * f1_; \
    ac[2] += W_ * f2_; ac[3] += W_ * f3_; \
} while (0)

__global__ __launch_bounds__(256, 6)
void fused_layer(const unsigned short* __restrict__ h, const unsigned char* __restrict__ h8,
                 const int* __restrict__ row_start,
                 const unsigned int* __restrict__ perm4, const unsigned short* __restrict__ Wp,
                 const float* __restrict__ bias, float* __restrict__ outF,
                 unsigned short* __restrict__ outB, unsigned char* __restrict__ outB8,
                 int relu) {
    __shared__ unsigned short Gs[16 * LDSROW];   // 4.25 KB
    const int tid  = threadIdx.x;
    const int lane = tid & 63;
    const int wid  = tid >> 6;
    const int g  = lane >> 4;      // node owner (phase1) / k-offset quad (phase2)
    const int sl = lane & 15;      // col-chunk (phase1) / A-row (phase2)
    const int rowT = blockIdx.x * 16;
    const int nodeBase = rowT + wid * 4;

    // row_start window for this wave's 4 nodes (one load, distribute by shfl)
    int rs = 0;
    if (lane < 5) rs = row_start[nodeBase + lane];
    const int beg = __shfl(rs, g, 64);
    const int end = __shfl(rs, g + 1, 64);

    // ---- phase 1: group g aggregates node nodeBase+g, dims [8sl, 8sl+8) ----
    floatx2 ac[4];
#pragma unroll
    for (int k = 0; k < 4; ++k) ac[k] = (floatx2){0.f, 0.f};
    const unsigned char* hp8 = h8 + sl * 8;
    const bool any = beg < end;
    unsigned int pA0 = 0, pA1 = 0, pA2 = 0, pA3 = 0;
    uint2 vA0 = {}, vA1 = {}, vA2 = {}, vA3 = {};
    int t = beg;
    if (any) {
        pA0 = perm4[t];
        pA1 = (t + 1 < end) ? perm4[t + 1] : 0u;   // p=0 -> src 0, w=+0
        pA2 = (t + 2 < end) ? perm4[t + 2] : 0u;
        pA3 = (t + 3 < end) ? perm4[t + 3] : 0u;
        vA0 = *(const uint2*)(hp8 + (size_t)(pA0 & 0xFFFFu) * DIM);
        vA1 = *(const uint2*)(hp8 + (size_t)(pA1 & 0xFFFFu) * DIM);
        vA2 = *(const uint2*)(hp8 + (size_t)(pA2 & 0xFFFFu) * DIM);
        vA3 = *(const uint2*)(hp8 + (size_t)(pA3 & 0xFFFFu) * DIM);
    }
    for (; t + 4 < end; t += 4) {
        unsigned int pB0 = perm4[t + 4];
        unsigned int pB1 = (t + 5 < end) ? perm4[t + 5] : 0u;
        unsigned int pB2 = (t + 6 < end) ? perm4[t + 6] : 0u;
        unsigned int pB3 = (t + 7 < end) ? perm4[t + 7] : 0u;
        uint2 vB0 = *(const uint2*)(hp8 + (size_t)(pB0 & 0xFFFFu) * DIM);
        uint2 vB1 = *(const uint2*)(hp8 + (size_t)(pB1 & 0xFFFFu) * DIM);
        uint2 vB2 = *(const uint2*)(hp8 + (size_t)(pB2 & 0xFFFFu) * DIM);
        uint2 vB3 = *(const uint2*)(hp8 + (size_t)(pB3 & 0xFFFFu) * DIM);
        ACCQ(pA0, vA0); ACCQ(pA1, vA1); ACCQ(pA2, vA2); ACCQ(pA3, vA3);
        pA0 = pB0; pA1 = pB1; pA2 = pB2; pA3 = pB3;
        vA0 = vB0; vA1 = vB1; vA2 = vB2; vA3 = vB3;
    }
    if (any) { ACCQ(pA0, vA0); ACCQ(pA1, vA1); ACCQ(pA2, vA2); ACCQ(pA3, vA3); }

    // group g's 16 lanes hold the full 128-dim aggregate of its node
    {
        uint4 r;
        r.x = (unsigned int)f2bf(ac[0].x) | ((unsigned int)f2bf(ac[0].y) << 16);
        r.y = (unsigned int)f2bf(ac[1].x) | ((unsigned int)f2bf(ac[1].y) << 16);
        r.z = (unsigned int)f2bf(ac[2].x) | ((unsigned int)f2bf(ac[2].y) << 16);
        r.w = (unsigned int)f2bf(ac[3].x) | ((unsigned int)f2bf(ac[3].y) << 16);
        *(uint4*)(&Gs[(wid * 4 + g) * LDSROW + sl * 8]) = r;
    }

    // ---- phase 1.5: root-GEMM half (h rows, no LDS dependency) ----
    floatx4 acc2[2];
#pragma unroll
    for (int ct = 0; ct < 2; ++ct) acc2[ct] = (floatx4){0.f, 0.f, 0.f, 0.f};
    const int rr = rowT + sl;          // grid exact: always < N
    const int ko = g * 8;
#pragma unroll
    for (int t2 = 4; t2 < 8; ++t2) {
        shortx8 a = *(const shortx8*)(h + (size_t)rr * DIM + (t2 - 4) * 32 + ko);
        const unsigned short* wp = Wp + (size_t)t2 * 4096 + (wid * 2) * 512 + lane * 8;
#pragma unroll
        for (int ct = 0; ct < 2; ++ct) {
            shortx8 b = *(const shortx8*)(wp + ct * 512);
            acc2[ct] = __builtin_amdgcn_mfma_f32_16x16x32_bf16(a, b, acc2[ct], 0, 0, 0);
        }
    }

    __syncthreads();   // waves now read rows written by other waves

    // ---- phase 2: aggregate-GEMM half from LDS ----
#pragma unroll
    for (int t2 = 0; t2 < 4; ++t2) {
        shortx8 a = *(const shortx8*)(&Gs[sl * LDSROW + t2 * 32 + ko]);
        const unsigned short* wp = Wp + (size_t)t2 * 4096 + (wid * 2) * 512 + lane * 8;
#pragma unroll
        for (int ct = 0; ct < 2; ++ct) {
            shortx8 b = *(const shortx8*)(wp + ct * 512);
            acc2[ct] = __builtin_amdgcn_mfma_f32_16x16x32_bf16(a, b, acc2[ct], 0, 0, 0);
        }
    }

#pragma unroll
    for (int ct = 0; ct < 2; ++ct) {
        int col = wid * 32 + ct * 16 + sl;
        float bv = bias[col];
#pragma unroll
        for (int i = 0; i < 4; ++i) {
            int row = rowT + g * 4 + i;
            float v = acc2[ct][i] + bv;
            if (relu) v = fmaxf(v, 0.f);
            if (outF) {
                outF[(size_t)row * DIM + col] = v;
            } else {
                outB[(size_t)row * DIM + col]  = f2bf(v);
                outB8[(size_t)row * DIM + col] = f2fp8(v);
            }
        }
    }
}

extern "C" void kernel_launch(void* const* d_in, const int* in_sizes, int n_in,
                              void* d_out, int out_size, void* d_ws, size_t ws_size,
                              hipStream_t stream) {
    const int N = N_NODES, E = N_EDGES;

    const float* x   = (const float*)d_in[0];
    const int*   ei  = (const int*)d_in[1];
    const float* ea  = (const float*)d_in[2];
    const float* wr0 = (const float*)d_in[3];
    const float* br0 = (const float*)d_in[4];
    const float* wt0 = (const float*)d_in[5];
    const float* wr1 = (const float*)d_in[6];
    const float* br1 = (const float*)d_in[7];
    const float* wt1 = (const float*)d_in[8];
    const float* wr2 = (const float*)d_in[9];
    const float* br2 = (const float*)d_in[10];
    const float* wt2 = (const float*)d_in[11];
    const int* srcI = ei;
    const int* dstI = ei + E;
    float* out = (float*)d_out;

    // workspace layout (bstage first for 8B alignment)
    int2* bstage = (int2*)d_ws;                              // NBUCK*BCAP int2 (8.8MB)
    unsigned short* X  = (unsigned short*)(bstage + (size_t)NBUCK * BCAP);  // N*128 bf16
    unsigned short* H1 = X + (size_t)N * DIM;                // N*128 bf16
    unsigned short* H2 = H1 + (size_t)N * DIM;               // N*128 bf16
    unsigned short* Wp = H2 + (size_t)N * DIM;               // 3*32768 bf16
    unsigned int* perm4 = (unsigned int*)(Wp + 3 * 32768);   // E u32
    int* bcursor = (int*)(perm4 + E);                        // NBUCK i32
    int* rowst   = bcursor + NBUCK;                          // N+1 i32
    unsigned char* X8  = (unsigned char*)(rowst + N_NODES + 1);  // N*128 fp8
    unsigned char* H81 = X8 + (size_t)N * DIM;               // N*128 fp8
    unsigned char* H82 = H81 + (size_t)N * DIM;              // N*128 fp8

    // prep (cvt + zero + pack) and CSR build via binned counting sort
    prep_kernel<<<CVT_BLOCKS + 1 + 384, 256, 0, stream>>>(x, X, X8, wr0, wt0, wr1, wt1, wr2, wt2, Wp, bcursor);
    partition_kernel<<<(E + CHUNK - 1) / CHUNK, 1024, 0, stream>>>(srcI, dstI, ea, bcursor, bstage, E);
    bucket_fill_kernel<<<NBUCK, 512, 0, stream>>>(bstage, bcursor, rowst, perm4, N);

    const int fusedGrid = N / 16;            // 3125 blocks, 16 rows each (exact)

    // ping-pong h buffers: gathers read prev layer's fp8 copy
    fused_layer<<<fusedGrid, 256, 0, stream>>>(X,  X8,  rowst, perm4, Wp,         br0, nullptr, H1, H81, 1);
    fused_layer<<<fusedGrid, 256, 0, stream>>>(H1, H81, rowst, perm4, Wp + 32768, br1, nullptr, H2, H82, 1);
    fused_layer<<<fusedGrid, 256, 0, stream>>>(H2, H82, rowst, perm4, Wp + 65536, br2, out, nullptr, nullptr, 0);
}

// Round 4
// 213.350 us; speedup vs baseline: 1.1436x; 1.0528x over previous
//
#include <hip/hip_runtime.h>
#include <hip/hip_bf16.h>
#include <hip/hip_fp16.h>

#define N_NODES 50000
#define N_EDGES 800000
#define DIM 128

#define NBUCK 391      // ceil(N/128) buckets of 128 consecutive dst nodes
#define BCAP  2816     // per-bucket staging capacity (mean 2046, sigma 45 -> +17 sigma)
#define CHUNK 2048     // edges per partition block (391 blocks)

#define CVT_BLOCKS 12500   // 12500*256*2 == N_NODES*DIM exactly (2 elems/thread)

#define LDSROW 136     // Gs row stride in shorts (272 B: 2-way bank alias = free)

typedef float floatx4 __attribute__((ext_vector_type(4)));
typedef float floatx2 __attribute__((ext_vector_type(2)));
typedef short shortx8 __attribute__((ext_vector_type(8)));

__device__ __forceinline__ unsigned short f2bf(float f) {
    union { float f; unsigned int u; } c; c.f = f;
    unsigned int u = c.u;
    unsigned int r = (u + 0x7FFFu + ((u >> 16) & 1u)) >> 16;
    return (unsigned short)r;
}
__device__ __forceinline__ unsigned char f2fp8(float f) {
    unsigned int p = __builtin_amdgcn_cvt_pk_fp8_f32(f, f, 0u, false);
    return (unsigned char)(p & 0xFFu);
}

// ---------------------------------------------------------------------------
// prep: fused  x->bf16+fp8 convert | zero bcursor | weight pack
__global__ __launch_bounds__(256)
void prep_kernel(const float* __restrict__ x, unsigned short* __restrict__ X,
                 unsigned char* __restrict__ X8,
                 const float* __restrict__ wr0, const float* __restrict__ wt0,
                 const float* __restrict__ wr1, const float* __restrict__ wt1,
                 const float* __restrict__ wr2, const float* __restrict__ wt2,
                 unsigned short* __restrict__ Wp, int* __restrict__ bcursor) {
    int b = blockIdx.x;
    if (b < CVT_BLOCKS) {
        int i = (b * 256 + threadIdx.x) * 2;   // N*DIM exact multiple of 512
        float2 xv = *(const float2*)(x + i);
        *(unsigned int*)(X + i) =
            (unsigned int)f2bf(xv.x) | ((unsigned int)f2bf(xv.y) << 16);
        unsigned int p8 = __builtin_amdgcn_cvt_pk_fp8_f32(xv.x, xv.y, 0u, false);
        *(unsigned short*)(X8 + i) = (unsigned short)(p8 & 0xFFFFu);
    } else if (b == CVT_BLOCKS) {
        for (int i = threadIdx.x; i < NBUCK; i += 256) bcursor[i] = 0;
    } else {
        int id = (b - CVT_BLOCKS - 1) * 256 + threadIdx.x;   // < 3*32768
        int layer = id >> 15;
        int rem = id & 32767;
        int j  = rem & 7;
        int L  = (rem >> 3) & 63;
        int ct = (rem >> 9) & 7;
        int t  = rem >> 12;
        int k = t * 32 + (L >> 4) * 8 + j;
        int c = ct * 16 + (L & 15);
        const float* wr = (layer == 0) ? wr0 : (layer == 1) ? wr1 : wr2;
        const float* wt = (layer == 0) ? wt0 : (layer == 1) ? wt1 : wt2;
        float v = (k < 128) ? wr[k * 128 + c] : wt[(k - 128) * 128 + c];
        Wp[id] = f2bf(v);
    }
}

// Pass 1: bin edges by bucket (dst>>7) through LDS, contiguous runs to staging.
__global__ __launch_bounds__(1024)
void partition_kernel(const int* __restrict__ src, const int* __restrict__ dst,
                      const float* __restrict__ ew,
                      int* __restrict__ bcursor, int2* __restrict__ bstage, int e) {
    __shared__ int2 stage[CHUNK];      // 16 KB
    __shared__ int cnt[NBUCK];
    __shared__ int lbase[NBUCK];
    __shared__ int gbase[NBUCK];
    __shared__ int wsum[16];
    const int tid = threadIdx.x;
    const int e0 = blockIdx.x * CHUNK;
    const int ecnt = min(CHUNK, e - e0);

    for (int i = tid; i < NBUCK; i += 1024) cnt[i] = 0;
    __syncthreads();
    for (int i = tid; i < ecnt; i += 1024)
        atomicAdd(&cnt[dst[e0 + i] >> 7], 1);
    __syncthreads();

    {
        int v = (tid < NBUCK) ? cnt[tid] : 0;
        int lane = tid & 63, wid = tid >> 6;
        int acc = v;
#pragma unroll
        for (int off = 1; off < 64; off <<= 1) {
            int t = __shfl_up(acc, off, 64);
            if (lane >= off) acc += t;
        }
        if (lane == 63) wsum[wid] = acc;
        __syncthreads();
        int wpref = 0;
        for (int w = 0; w < wid; ++w) wpref += wsum[w];
        int excl = wpref + acc - v;
        if (tid < NBUCK) {
            lbase[tid] = excl;
            gbase[tid] = atomicAdd(&bcursor[tid], v);
            cnt[tid] = 0;            // reuse as local cursor
        }
    }
    __syncthreads();

    for (int i = tid; i < ecnt; i += 1024) {
        int d = dst[e0 + i];
        int s = src[e0 + i];
        unsigned int hw = (unsigned int)__half_as_ushort(__float2half(ew[e0 + i]));
        int b = d >> 7;
        int pos = atomicAdd(&cnt[b], 1);
        stage[lbase[b] + pos] = make_int2((int)((hw << 16) | (unsigned int)s), d);
    }
    __syncthreads();

    for (int j = tid; j < ecnt; j += 1024) {
        int2 p = stage[j];
        int b = p.y >> 7;
        int gidx = b * BCAP + gbase[b] + (j - lbase[b]);
        bstage[gidx] = p;
    }
}

// Pass 2: per bucket (128 nodes, 391 blocks), 512 threads.
__global__ __launch_bounds__(512)
void bucket_fill_kernel(const int2* __restrict__ bstage, const int* __restrict__ bcursor,
                        int* __restrict__ row_start, unsigned int* __restrict__ perm4, int n) {
    __shared__ int cnt128[128];
    __shared__ int curs[128];
    __shared__ int wsum[8];
    __shared__ int sbase, scnt;
    const int tid = threadIdx.x;
    const int b = blockIdx.x;
    const int node0 = b << 7;
    const int lane = tid & 63, wid = tid >> 6;

    // exclusive prefix over 391 bucket totals, 1 entry per thread (512 >= 391)
    {
        int v = (tid < NBUCK) ? bcursor[tid] : 0;
        int acc = v;
#pragma unroll
        for (int off = 1; off < 64; off <<= 1) {
            int t = __shfl_up(acc, off, 64);
            if (lane >= off) acc += t;
        }
        if (lane == 63) wsum[wid] = acc;
        __syncthreads();
        int wpref = 0;
        for (int w = 0; w < wid; ++w) wpref += wsum[w];
        int excl = wpref + acc - v;
        if (tid == b) { sbase = excl; scnt = v; }
    }
    __syncthreads();
    const int cntb = scnt;
    const int base = sbase;
    const int2* sp = bstage + (size_t)b * BCAP;

    if (tid < 128) cnt128[tid] = 0;
    __syncthreads();
    for (int i = tid; i < cntb; i += 512)
        atomicAdd(&cnt128[sp[i].y & 127], 1);
    __syncthreads();

    // scan 128 per-node counts (first 2 waves carry data)
    int v = (tid < 128) ? cnt128[tid] : 0;
    int acc = v;
#pragma unroll
    for (int off = 1; off < 64; off <<= 1) {
        int t = __shfl_up(acc, off, 64);
        if (lane >= off) acc += t;
    }
    if (lane == 63) wsum[wid] = acc;
    __syncthreads();
    int wpref = 0;
    for (int w = 0; w < wid; ++w) wpref += wsum[w];
    int excl = wpref + acc - v;
    if (tid < 128) {
        int node = node0 + tid;
        if (node <= n) row_start[node] = base + excl;
        curs[tid] = excl;
    }
    __syncthreads();

    for (int i = tid; i < cntb; i += 512) {
        int2 p = sp[i];
        int pos = atomicAdd(&curs[p.y & 127], 1);
        perm4[base + pos] = (unsigned int)p.x;
    }
}

// ---------------------------------------------------------------------------
// Fused layer v8: fp8 gather path, 128B-ALIGNED fp8 tables (2 lines/row, was 3).
// Phase 1: lane-group g owns node nodeBase+g; 2-deep software pipeline.
// Phase 1.5: root-GEMM half before the barrier (no LDS dep).
// Phase 2: aggregate-GEMM half from LDS.
#define ACCQ(p, v) do { \
    float w_ = __half2float(__ushort_as_half((unsigned short)((p) >> 16))); \
    floatx2 W_ = (floatx2){w_, w_}; \
    floatx2 f0_ = __builtin_amdgcn_cvt_pk_f32_fp8((v).x, false); \
    floatx2 f1_ = __builtin_amdgcn_cvt_pk_f32_fp8((v).x, true);  \
    floatx2 f2_ = __builtin_amdgcn_cvt_pk_f32_fp8((v).y, false); \
    floatx2 f3_ = __builtin_amdgcn_cvt_pk_f32_fp8((v).y, true);  \
    ac[0] += W_ * f0_; ac[1] += W_ * f1_; \
    ac[2] += W_ * f2_; ac[3] += W_ * f3_; \
} while (0)

__global__ __launch_bounds__(256, 6)
void fused_layer(const unsigned short* __restrict__ h, const unsigned char* __restrict__ h8,
                 const int* __restrict__ row_start,
                 const unsigned int* __restrict__ perm4, const unsigned short* __restrict__ Wp,
                 const float* __restrict__ bias, float* __restrict__ outF,
                 unsigned short* __restrict__ outB, unsigned char* __restrict__ outB8,
                 int relu) {
    __shared__ unsigned short Gs[16 * LDSROW];   // 4.25 KB
    const int tid  = threadIdx.x;
    const int lane = tid & 63;
    const int wid  = tid >> 6;
    const int g  = lane >> 4;      // node owner (phase1) / k-offset quad (phase2)
    const int sl = lane & 15;      // col-chunk (phase1) / A-row (phase2)
    const int rowT = blockIdx.x * 16;
    const int nodeBase = rowT + wid * 4;

    // row_start window for this wave's 4 nodes (one load, distribute by shfl)
    int rs = 0;
    if (lane < 5) rs = row_start[nodeBase + lane];
    const int beg = __shfl(rs, g, 64);
    const int end = __shfl(rs, g + 1, 64);

    // ---- phase 1: group g aggregates node nodeBase+g, dims [8sl, 8sl+8) ----
    floatx2 ac[4];
#pragma unroll
    for (int k = 0; k < 4; ++k) ac[k] = (floatx2){0.f, 0.f};
    const unsigned char* hp8 = h8 + sl * 8;
    const bool any = beg < end;
    unsigned int pA0 = 0, pA1 = 0, pA2 = 0, pA3 = 0;
    uint2 vA0 = {}, vA1 = {}, vA2 = {}, vA3 = {};
    int t = beg;
    if (any) {
        pA0 = perm4[t];
        pA1 = (t + 1 < end) ? perm4[t + 1] : 0u;   // p=0 -> src 0, w=+0
        pA2 = (t + 2 < end) ? perm4[t + 2] : 0u;
        pA3 = (t + 3 < end) ? perm4[t + 3] : 0u;
        vA0 = *(const uint2*)(hp8 + (size_t)(pA0 & 0xFFFFu) * DIM);
        vA1 = *(const uint2*)(hp8 + (size_t)(pA1 & 0xFFFFu) * DIM);
        vA2 = *(const uint2*)(hp8 + (size_t)(pA2 & 0xFFFFu) * DIM);
        vA3 = *(const uint2*)(hp8 + (size_t)(pA3 & 0xFFFFu) * DIM);
    }
    for (; t + 4 < end; t += 4) {
        unsigned int pB0 = perm4[t + 4];
        unsigned int pB1 = (t + 5 < end) ? perm4[t + 5] : 0u;
        unsigned int pB2 = (t + 6 < end) ? perm4[t + 6] : 0u;
        unsigned int pB3 = (t + 7 < end) ? perm4[t + 7] : 0u;
        uint2 vB0 = *(const uint2*)(hp8 + (size_t)(pB0 & 0xFFFFu) * DIM);
        uint2 vB1 = *(const uint2*)(hp8 + (size_t)(pB1 & 0xFFFFu) * DIM);
        uint2 vB2 = *(const uint2*)(hp8 + (size_t)(pB2 & 0xFFFFu) * DIM);
        uint2 vB3 = *(const uint2*)(hp8 + (size_t)(pB3 & 0xFFFFu) * DIM);
        ACCQ(pA0, vA0); ACCQ(pA1, vA1); ACCQ(pA2, vA2); ACCQ(pA3, vA3);
        pA0 = pB0; pA1 = pB1; pA2 = pB2; pA3 = pB3;
        vA0 = vB0; vA1 = vB1; vA2 = vB2; vA3 = vB3;
    }
    if (any) { ACCQ(pA0, vA0); ACCQ(pA1, vA1); ACCQ(pA2, vA2); ACCQ(pA3, vA3); }

    // group g's 16 lanes hold the full 128-dim aggregate of its node
    {
        uint4 r;
        r.x = (unsigned int)f2bf(ac[0].x) | ((unsigned int)f2bf(ac[0].y) << 16);
        r.y = (unsigned int)f2bf(ac[1].x) | ((unsigned int)f2bf(ac[1].y) << 16);
        r.z = (unsigned int)f2bf(ac[2].x) | ((unsigned int)f2bf(ac[2].y) << 16);
        r.w = (unsigned int)f2bf(ac[3].x) | ((unsigned int)f2bf(ac[3].y) << 16);
        *(uint4*)(&Gs[(wid * 4 + g) * LDSROW + sl * 8]) = r;
    }

    // ---- phase 1.5: root-GEMM half (h rows, no LDS dependency) ----
    floatx4 acc2[2];
#pragma unroll
    for (int ct = 0; ct < 2; ++ct) acc2[ct] = (floatx4){0.f, 0.f, 0.f, 0.f};
    const int rr = rowT + sl;          // grid exact: always < N
    const int ko = g * 8;
#pragma unroll
    for (int t2 = 4; t2 < 8; ++t2) {
        shortx8 a = *(const shortx8*)(h + (size_t)rr * DIM + (t2 - 4) * 32 + ko);
        const unsigned short* wp = Wp + (size_t)t2 * 4096 + (wid * 2) * 512 + lane * 8;
#pragma unroll
        for (int ct = 0; ct < 2; ++ct) {
            shortx8 b = *(const shortx8*)(wp + ct * 512);
            acc2[ct] = __builtin_amdgcn_mfma_f32_16x16x32_bf16(a, b, acc2[ct], 0, 0, 0);
        }
    }

    __syncthreads();   // waves now read rows written by other waves

    // ---- phase 2: aggregate-GEMM half from LDS ----
#pragma unroll
    for (int t2 = 0; t2 < 4; ++t2) {
        shortx8 a = *(const shortx8*)(&Gs[sl * LDSROW + t2 * 32 + ko]);
        const unsigned short* wp = Wp + (size_t)t2 * 4096 + (wid * 2) * 512 + lane * 8;
#pragma unroll
        for (int ct = 0; ct < 2; ++ct) {
            shortx8 b = *(const shortx8*)(wp + ct * 512);
            acc2[ct] = __builtin_amdgcn_mfma_f32_16x16x32_bf16(a, b, acc2[ct], 0, 0, 0);
        }
    }

#pragma unroll
    for (int ct = 0; ct < 2; ++ct) {
        int col = wid * 32 + ct * 16 + sl;
        float bv = bias[col];
#pragma unroll
        for (int i = 0; i < 4; ++i) {
            int row = rowT + g * 4 + i;
            float v = acc2[ct][i] + bv;
            if (relu) v = fmaxf(v, 0.f);
            if (outF) {
                outF[(size_t)row * DIM + col] = v;
            } else {
                outB[(size_t)row * DIM + col]  = f2bf(v);
                outB8[(size_t)row * DIM + col] = f2fp8(v);
            }
        }
    }
}

extern "C" void kernel_launch(void* const* d_in, const int* in_sizes, int n_in,
                              void* d_out, int out_size, void* d_ws, size_t ws_size,
                              hipStream_t stream) {
    const int N = N_NODES, E = N_EDGES;

    const float* x   = (const float*)d_in[0];
    const int*   ei  = (const int*)d_in[1];
    const float* ea  = (const float*)d_in[2];
    const float* wr0 = (const float*)d_in[3];
    const float* br0 = (const float*)d_in[4];
    const float* wt0 = (const float*)d_in[5];
    const float* wr1 = (const float*)d_in[6];
    const float* br1 = (const float*)d_in[7];
    const float* wt1 = (const float*)d_in[8];
    const float* wr2 = (const float*)d_in[9];
    const float* br2 = (const float*)d_in[10];
    const float* wt2 = (const float*)d_in[11];
    const int* srcI = ei;
    const int* dstI = ei + E;
    float* out = (float*)d_out;

    // workspace layout — every array before the fp8 tables has a size that is
    // a multiple of 128 B, so X8/H81/H82 rows are 128B-aligned (2 lines/row).
    int2* bstage = (int2*)d_ws;                              // 391*2816*8 = 8,808,448 B
    unsigned short* X  = (unsigned short*)(bstage + (size_t)NBUCK * BCAP);  // 12.8 MB
    unsigned short* H1 = X + (size_t)N * DIM;                // 12.8 MB
    unsigned short* H2 = H1 + (size_t)N * DIM;               // 12.8 MB
    unsigned short* Wp = H2 + (size_t)N * DIM;               // 196,608 B
    unsigned char* X8  = (unsigned char*)(Wp + 3 * 32768);   // 6.4 MB (128B-aligned)
    unsigned char* H81 = X8 + (size_t)N * DIM;               // 6.4 MB
    unsigned char* H82 = H81 + (size_t)N * DIM;              // 6.4 MB
    unsigned int* perm4 = (unsigned int*)(H82 + (size_t)N * DIM);  // E u32
    int* bcursor = (int*)(perm4 + E);                        // NBUCK i32
    int* rowst   = bcursor + NBUCK;                          // N+1 i32

    // prep (cvt + zero + pack) and CSR build via binned counting sort
    prep_kernel<<<CVT_BLOCKS + 1 + 384, 256, 0, stream>>>(x, X, X8, wr0, wt0, wr1, wt1, wr2, wt2, Wp, bcursor);
    partition_kernel<<<(E + CHUNK - 1) / CHUNK, 1024, 0, stream>>>(srcI, dstI, ea, bcursor, bstage, E);
    bucket_fill_kernel<<<NBUCK, 512, 0, stream>>>(bstage, bcursor, rowst, perm4, N);

    const int fusedGrid = N / 16;            // 3125 blocks, 16 rows each (exact)

    // ping-pong h buffers: gathers read prev layer's fp8 copy
    fused_layer<<<fusedGrid, 256, 0, stream>>>(X,  X8,  rowst, perm4, Wp,         br0, nullptr, H1, H81, 1);
    fused_layer<<<fusedGrid, 256, 0, stream>>>(H1, H81, rowst, perm4, Wp + 32768, br1, nullptr, H2, H82, 1);
    fused_layer<<<fusedGrid, 256, 0, stream>>>(H2, H82, rowst, perm4, Wp + 65536, br2, out, nullptr, nullptr, 0);
}

// Round 5
// 211.816 us; speedup vs baseline: 1.1519x; 1.0072x over previous
//
#include <hip/hip_runtime.h>
#include <hip/hip_bf16.h>
#include <hip/hip_fp16.h>

#define N_NODES 50000
#define N_EDGES 800000
#define DIM 128

#define NBUCK 391      // ceil(N/128) buckets of 128 consecutive dst nodes
#define BCAP  2816     // per-bucket staging capacity (mean 2046, sigma 45 -> +17 sigma)
#define CHUNK 2048     // edges per partition block (391 blocks)
#define BSLACK 384     // per-bucket perm4 padding slack (128 nodes * 3 max pad)

#define CVT_BLOCKS 12500   // 12500*256*2 == N_NODES*DIM exactly (2 elems/thread)

#define LDSROW 136     // Gs row stride in shorts (272 B: 2-way bank alias = free)

typedef float floatx4 __attribute__((ext_vector_type(4)));
typedef float floatx2 __attribute__((ext_vector_type(2)));
typedef short shortx8 __attribute__((ext_vector_type(8)));

__device__ __forceinline__ unsigned short f2bf(float f) {
    union { float f; unsigned int u; } c; c.f = f;
    unsigned int u = c.u;
    unsigned int r = (u + 0x7FFFu + ((u >> 16) & 1u)) >> 16;
    return (unsigned short)r;
}
__device__ __forceinline__ unsigned char f2fp8(float f) {
    unsigned int p = __builtin_amdgcn_cvt_pk_fp8_f32(f, f, 0u, false);
    return (unsigned char)(p & 0xFFu);
}

// ---------------------------------------------------------------------------
// prep: fused  x->bf16+fp8 convert | zero bcursor | weight pack
__global__ __launch_bounds__(256)
void prep_kernel(const float* __restrict__ x, unsigned short* __restrict__ X,
                 unsigned char* __restrict__ X8,
                 const float* __restrict__ wr0, const float* __restrict__ wt0,
                 const float* __restrict__ wr1, const float* __restrict__ wt1,
                 const float* __restrict__ wr2, const float* __restrict__ wt2,
                 unsigned short* __restrict__ Wp, int* __restrict__ bcursor) {
    int b = blockIdx.x;
    if (b < CVT_BLOCKS) {
        int i = (b * 256 + threadIdx.x) * 2;   // N*DIM exact multiple of 512
        float2 xv = *(const float2*)(x + i);
        *(unsigned int*)(X + i) =
            (unsigned int)f2bf(xv.x) | ((unsigned int)f2bf(xv.y) << 16);
        unsigned int p8 = __builtin_amdgcn_cvt_pk_fp8_f32(xv.x, xv.y, 0u, false);
        *(unsigned short*)(X8 + i) = (unsigned short)(p8 & 0xFFFFu);
    } else if (b == CVT_BLOCKS) {
        for (int i = threadIdx.x; i < NBUCK; i += 256) bcursor[i] = 0;
    } else {
        int id = (b - CVT_BLOCKS - 1) * 256 + threadIdx.x;   // < 3*32768
        int layer = id >> 15;
        int rem = id & 32767;
        int j  = rem & 7;
        int L  = (rem >> 3) & 63;
        int ct = (rem >> 9) & 7;
        int t  = rem >> 12;
        int k = t * 32 + (L >> 4) * 8 + j;
        int c = ct * 16 + (L & 15);
        const float* wr = (layer == 0) ? wr0 : (layer == 1) ? wr1 : wr2;
        const float* wt = (layer == 0) ? wt0 : (layer == 1) ? wt1 : wt2;
        float v = (k < 128) ? wr[k * 128 + c] : wt[(k - 128) * 128 + c];
        Wp[id] = f2bf(v);
    }
}

// Pass 1: bin edges by bucket (dst>>7) through LDS, contiguous runs to staging.
__global__ __launch_bounds__(1024)
void partition_kernel(const int* __restrict__ src, const int* __restrict__ dst,
                      const float* __restrict__ ew,
                      int* __restrict__ bcursor, int2* __restrict__ bstage, int e) {
    __shared__ int2 stage[CHUNK];      // 16 KB
    __shared__ int cnt[NBUCK];
    __shared__ int lbase[NBUCK];
    __shared__ int gbase[NBUCK];
    __shared__ int wsum[16];
    const int tid = threadIdx.x;
    const int e0 = blockIdx.x * CHUNK;
    const int ecnt = min(CHUNK, e - e0);

    for (int i = tid; i < NBUCK; i += 1024) cnt[i] = 0;
    __syncthreads();
    for (int i = tid; i < ecnt; i += 1024)
        atomicAdd(&cnt[dst[e0 + i] >> 7], 1);
    __syncthreads();

    {
        int v = (tid < NBUCK) ? cnt[tid] : 0;
        int lane = tid & 63, wid = tid >> 6;
        int acc = v;
#pragma unroll
        for (int off = 1; off < 64; off <<= 1) {
            int t = __shfl_up(acc, off, 64);
            if (lane >= off) acc += t;
        }
        if (lane == 63) wsum[wid] = acc;
        __syncthreads();
        int wpref = 0;
        for (int w = 0; w < wid; ++w) wpref += wsum[w];
        int excl = wpref + acc - v;
        if (tid < NBUCK) {
            lbase[tid] = excl;
            gbase[tid] = atomicAdd(&bcursor[tid], v);
            cnt[tid] = 0;            // reuse as local cursor
        }
    }
    __syncthreads();

    for (int i = tid; i < ecnt; i += 1024) {
        int d = dst[e0 + i];
        int s = src[e0 + i];
        unsigned int hw = (unsigned int)__half_as_ushort(__float2half(ew[e0 + i]));
        int b = d >> 7;
        int pos = atomicAdd(&cnt[b], 1);
        stage[lbase[b] + pos] = make_int2((int)((hw << 16) | (unsigned int)s), d);
    }
    __syncthreads();

    for (int j = tid; j < ecnt; j += 1024) {
        int2 p = stage[j];
        int b = p.y >> 7;
        int gidx = b * BCAP + gbase[b] + (j - lbase[b]);
        bstage[gidx] = p;
    }
}

// Pass 2: per bucket (128 nodes, 391 blocks), 512 threads.
// Per-node lists in perm4 are padded to a multiple of 4 (pad entries = 0:
// src 0, weight +0.0). Bucket b's perm4 window starts at rawScan(b) + b*BSLACK.
// row_start/row_end give each node's padded [beg,end).
__global__ __launch_bounds__(512)
void bucket_fill_kernel(const int2* __restrict__ bstage, const int* __restrict__ bcursor,
                        int* __restrict__ row_start, int* __restrict__ row_end,
                        unsigned int* __restrict__ perm4, int n) {
    __shared__ int cnt128[128];
    __shared__ int curs[128];
    __shared__ int wsum[8];
    __shared__ int sbase, scnt;
    const int tid = threadIdx.x;
    const int b = blockIdx.x;
    const int node0 = b << 7;
    const int lane = tid & 63, wid = tid >> 6;

    // exclusive prefix over 391 raw bucket totals, 1 entry per thread
    {
        int v = (tid < NBUCK) ? bcursor[tid] : 0;
        int acc = v;
#pragma unroll
        for (int off = 1; off < 64; off <<= 1) {
            int t = __shfl_up(acc, off, 64);
            if (lane >= off) acc += t;
        }
        if (lane == 63) wsum[wid] = acc;
        __syncthreads();
        int wpref = 0;
        for (int w = 0; w < wid; ++w) wpref += wsum[w];
        int excl = wpref + acc - v;
        if (tid == b) { sbase = excl; scnt = v; }
    }
    __syncthreads();
    const int cntb = scnt;
    const int base = sbase + b * BSLACK;     // padded slack per bucket
    const int2* sp = bstage + (size_t)b * BCAP;

    if (tid < 128) cnt128[tid] = 0;
    __syncthreads();
    for (int i = tid; i < cntb; i += 512)
        atomicAdd(&cnt128[sp[i].y & 127], 1);
    __syncthreads();

    // scan 128 per-node PADDED counts (first 2 waves carry data)
    int v = (tid < 128) ? cnt128[tid] : 0;
    int pcv = (v + 3) & ~3;
    int acc = pcv;
#pragma unroll
    for (int off = 1; off < 64; off <<= 1) {
        int t = __shfl_up(acc, off, 64);
        if (lane >= off) acc += t;
    }
    if (lane == 63) wsum[wid] = acc;
    __syncthreads();
    int wpref = 0;
    for (int w = 0; w < wid; ++w) wpref += wsum[w];
    int excl = wpref + acc - pcv;
    if (tid < 128) {
        int node = node0 + tid;
        if (node < n) {
            row_start[node] = base + excl;
            row_end[node]   = base + excl + pcv;
        }
        curs[tid] = excl;
        // zero-fill the <=3 pad slots so they read as (src 0, weight +0.0)
        for (int k = v; k < pcv; ++k) perm4[base + excl + k] = 0u;
    }
    __syncthreads();

    for (int i = tid; i < cntb; i += 512) {
        int2 p = sp[i];
        int pos = atomicAdd(&curs[p.y & 127], 1);
        perm4[base + pos] = (unsigned int)p.x;
    }
}

// ---------------------------------------------------------------------------
// Fused layer v9: guard-free quad gather loop.
// Per-node perm lists are padded to x4, so phase 1 has NO per-edge bounds
// checks, and each quad's 4 perm entries load as ONE 16B dwordx4 broadcast
// (beg is a multiple of 4 -> 16B-aligned).
// Phase 1: lane-group g owns node nodeBase+g; 2-deep software pipeline.
// Phase 1.5: root-GEMM half before the barrier (no LDS dep).
// Phase 2: aggregate-GEMM half from LDS.
#define ACCQ(p, v) do { \
    float w_ = __half2float(__ushort_as_half((unsigned short)((p) >> 16))); \
    floatx2 W_ = (floatx2){w_, w_}; \
    floatx2 f0_ = __builtin_amdgcn_cvt_pk_f32_fp8((v).x, false); \
    floatx2 f1_ = __builtin_amdgcn_cvt_pk_f32_fp8((v).x, true);  \
    floatx2 f2_ = __builtin_amdgcn_cvt_pk_f32_fp8((v).y, false); \
    floatx2 f3_ = __builtin_amdgcn_cvt_pk_f32_fp8((v).y, true);  \
    ac[0] += W_ * f0_; ac[1] += W_ * f1_; \
    ac[2] += W_ * f2_; ac[3] += W_ * f3_; \
} while (0)

__global__ __launch_bounds__(256, 6)
void fused_layer(const unsigned short* __restrict__ h, const unsigned char* __restrict__ h8,
                 const int* __restrict__ row_start, const int* __restrict__ row_end,
                 const unsigned int* __restrict__ perm4, const unsigned short* __restrict__ Wp,
                 const float* __restrict__ bias, float* __restrict__ outF,
                 unsigned short* __restrict__ outB, unsigned char* __restrict__ outB8,
                 int relu) {
    __shared__ unsigned short Gs[16 * LDSROW];   // 4.25 KB
    const int tid  = threadIdx.x;
    const int lane = tid & 63;
    const int wid  = tid >> 6;
    const int g  = lane >> 4;      // node owner (phase1) / k-offset quad (phase2)
    const int sl = lane & 15;      // col-chunk (phase1) / A-row (phase2)
    const int rowT = blockIdx.x * 16;
    const int nodeBase = rowT + wid * 4;

    // beg/end for the wave's 4 nodes: lanes 0-3 load row_start, 4-7 row_end
    int rs = 0;
    {
        int idx = nodeBase + (lane & 3);
        if (lane < 4)      rs = row_start[idx];
        else if (lane < 8) rs = row_end[idx];
    }
    const int beg = __shfl(rs, g, 64);
    const int end = __shfl(rs, g + 4, 64);

    // ---- phase 1: group g aggregates node nodeBase+g, dims [8sl, 8sl+8) ----
    floatx2 ac[4];
#pragma unroll
    for (int k = 0; k < 4; ++k) ac[k] = (floatx2){0.f, 0.f};
    const unsigned char* hp8 = h8 + sl * 8;
    const bool any = beg < end;
    uint4 P = {};
    uint2 v0 = {}, v1 = {}, v2 = {}, v3 = {};
    int t = beg;
    if (any) {
        P  = *(const uint4*)(perm4 + t);     // 16B broadcast: all 16 lanes same addr
        v0 = *(const uint2*)(hp8 + (size_t)(P.x & 0xFFFFu) * DIM);
        v1 = *(const uint2*)(hp8 + (size_t)(P.y & 0xFFFFu) * DIM);
        v2 = *(const uint2*)(hp8 + (size_t)(P.z & 0xFFFFu) * DIM);
        v3 = *(const uint2*)(hp8 + (size_t)(P.w & 0xFFFFu) * DIM);
    }
    for (; t + 4 < end; t += 4) {
        uint4 Pn = *(const uint4*)(perm4 + t + 4);
        uint2 w0 = *(const uint2*)(hp8 + (size_t)(Pn.x & 0xFFFFu) * DIM);
        uint2 w1 = *(const uint2*)(hp8 + (size_t)(Pn.y & 0xFFFFu) * DIM);
        uint2 w2 = *(const uint2*)(hp8 + (size_t)(Pn.z & 0xFFFFu) * DIM);
        uint2 w3 = *(const uint2*)(hp8 + (size_t)(Pn.w & 0xFFFFu) * DIM);
        ACCQ(P.x, v0); ACCQ(P.y, v1); ACCQ(P.z, v2); ACCQ(P.w, v3);
        P = Pn;
        v0 = w0; v1 = w1; v2 = w2; v3 = w3;
    }
    if (any) { ACCQ(P.x, v0); ACCQ(P.y, v1); ACCQ(P.z, v2); ACCQ(P.w, v3); }

    // group g's 16 lanes hold the full 128-dim aggregate of its node
    {
        uint4 r;
        r.x = (unsigned int)f2bf(ac[0].x) | ((unsigned int)f2bf(ac[0].y) << 16);
        r.y = (unsigned int)f2bf(ac[1].x) | ((unsigned int)f2bf(ac[1].y) << 16);
        r.z = (unsigned int)f2bf(ac[2].x) | ((unsigned int)f2bf(ac[2].y) << 16);
        r.w = (unsigned int)f2bf(ac[3].x) | ((unsigned int)f2bf(ac[3].y) << 16);
        *(uint4*)(&Gs[(wid * 4 + g) * LDSROW + sl * 8]) = r;
    }

    // ---- phase 1.5: root-GEMM half (h rows, no LDS dependency) ----
    floatx4 acc2[2];
#pragma unroll
    for (int ct = 0; ct < 2; ++ct) acc2[ct] = (floatx4){0.f, 0.f, 0.f, 0.f};
    const int rr = rowT + sl;          // grid exact: always < N
    const int ko = g * 8;
#pragma unroll
    for (int t2 = 4; t2 < 8; ++t2) {
        shortx8 a = *(const shortx8*)(h + (size_t)rr * DIM + (t2 - 4) * 32 + ko);
        const unsigned short* wp = Wp + (size_t)t2 * 4096 + (wid * 2) * 512 + lane * 8;
#pragma unroll
        for (int ct = 0; ct < 2; ++ct) {
            shortx8 b = *(const shortx8*)(wp + ct * 512);
            acc2[ct] = __builtin_amdgcn_mfma_f32_16x16x32_bf16(a, b, acc2[ct], 0, 0, 0);
        }
    }

    __syncthreads();   // waves now read rows written by other waves

    // ---- phase 2: aggregate-GEMM half from LDS ----
#pragma unroll
    for (int t2 = 0; t2 < 4; ++t2) {
        shortx8 a = *(const shortx8*)(&Gs[sl * LDSROW + t2 * 32 + ko]);
        const unsigned short* wp = Wp + (size_t)t2 * 4096 + (wid * 2) * 512 + lane * 8;
#pragma unroll
        for (int ct = 0; ct < 2; ++ct) {
            shortx8 b = *(const shortx8*)(wp + ct * 512);
            acc2[ct] = __builtin_amdgcn_mfma_f32_16x16x32_bf16(a, b, acc2[ct], 0, 0, 0);
        }
    }

#pragma unroll
    for (int ct = 0; ct < 2; ++ct) {
        int col = wid * 32 + ct * 16 + sl;
        float bv = bias[col];
#pragma unroll
        for (int i = 0; i < 4; ++i) {
            int row = rowT + g * 4 + i;
            float v = acc2[ct][i] + bv;
            if (relu) v = fmaxf(v, 0.f);
            if (outF) {
                outF[(size_t)row * DIM + col] = v;
            } else {
                outB[(size_t)row * DIM + col]  = f2bf(v);
                outB8[(size_t)row * DIM + col] = f2fp8(v);
            }
        }
    }
}

extern "C" void kernel_launch(void* const* d_in, const int* in_sizes, int n_in,
                              void* d_out, int out_size, void* d_ws, size_t ws_size,
                              hipStream_t stream) {
    const int N = N_NODES, E = N_EDGES;

    const float* x   = (const float*)d_in[0];
    const int*   ei  = (const int*)d_in[1];
    const float* ea  = (const float*)d_in[2];
    const float* wr0 = (const float*)d_in[3];
    const float* br0 = (const float*)d_in[4];
    const float* wt0 = (const float*)d_in[5];
    const float* wr1 = (const float*)d_in[6];
    const float* br1 = (const float*)d_in[7];
    const float* wt1 = (const float*)d_in[8];
    const float* wr2 = (const float*)d_in[9];
    const float* br2 = (const float*)d_in[10];
    const float* wt2 = (const float*)d_in[11];
    const int* srcI = ei;
    const int* dstI = ei + E;
    float* out = (float*)d_out;

    // workspace layout — every array before the fp8 tables has a size that is
    // a multiple of 128 B, so X8/H81/H82 rows are 128B-aligned (2 lines/row),
    // and perm4 is 128B-aligned (dwordx4 quad loads).
    int2* bstage = (int2*)d_ws;                              // 391*2816*8 = 8,808,448 B
    unsigned short* X  = (unsigned short*)(bstage + (size_t)NBUCK * BCAP);  // 12.8 MB
    unsigned short* H1 = X + (size_t)N * DIM;                // 12.8 MB
    unsigned short* H2 = H1 + (size_t)N * DIM;               // 12.8 MB
    unsigned short* Wp = H2 + (size_t)N * DIM;               // 196,608 B
    unsigned char* X8  = (unsigned char*)(Wp + 3 * 32768);   // 6.4 MB (128B-aligned)
    unsigned char* H81 = X8 + (size_t)N * DIM;               // 6.4 MB
    unsigned char* H82 = H81 + (size_t)N * DIM;              // 6.4 MB
    unsigned int* perm4 = (unsigned int*)(H82 + (size_t)N * DIM);  // E + NBUCK*BSLACK (<1M) u32
    int* bcursor = (int*)(perm4 + 1000000);                  // NBUCK i32
    int* rowst   = bcursor + NBUCK;                          // N i32
    int* rowend  = rowst + N_NODES;                          // N i32

    // prep (cvt + zero + pack) and CSR build via binned counting sort
    prep_kernel<<<CVT_BLOCKS + 1 + 384, 256, 0, stream>>>(x, X, X8, wr0, wt0, wr1, wt1, wr2, wt2, Wp, bcursor);
    partition_kernel<<<(E + CHUNK - 1) / CHUNK, 1024, 0, stream>>>(srcI, dstI, ea, bcursor, bstage, E);
    bucket_fill_kernel<<<NBUCK, 512, 0, stream>>>(bstage, bcursor, rowst, rowend, perm4, N);

    const int fusedGrid = N / 16;            // 3125 blocks, 16 rows each (exact)

    // ping-pong h buffers: gathers read prev layer's fp8 copy
    fused_layer<<<fusedGrid, 256, 0, stream>>>(X,  X8,  rowst, rowend, perm4, Wp,         br0, nullptr, H1, H81, 1);
    fused_layer<<<fusedGrid, 256, 0, stream>>>(H1, H81, rowst, rowend, perm4, Wp + 32768, br1, nullptr, H2, H82, 1);
    fused_layer<<<fusedGrid, 256, 0, stream>>>(H2, H82, rowst, rowend, perm4, Wp + 65536, br2, out, nullptr, nullptr, 0);
}